// Round 1
// baseline (335.327 us; speedup 1.0000x reference)
//
#include <hip/hip_runtime.h>
#include <hip/hip_bf16.h>

typedef float  f32x4  __attribute__((ext_vector_type(4)));
typedef __bf16 bf16x8 __attribute__((ext_vector_type(8)));

#define MFMA16(A,B,C) __builtin_amdgcn_mfma_f32_16x16x32_bf16((A),(B),(C),0,0,0)

static constexpr int Tn = 2048, Bn = 2, En = 1024, Hn = 16, Dn = 64;

// ---------------------------------------------------------------------------
// Kernel 1: fused QKV in-projection.  C[i,o] = X[i,:] . W[o,:] + bias[o]
// i = t*B + b (M=4096), o in [0,3072) (which = o/1024 selects X and dest).
// Output scattered as bf16 [B,H,T,D].
// ---------------------------------------------------------------------------
__global__ __launch_bounds__(256)
void k_qkv(const float* __restrict__ Xq, const float* __restrict__ Xk,
           const float* __restrict__ Xv, const float* __restrict__ W,
           const float* __restrict__ bias,
           __bf16* __restrict__ q_ws, __bf16* __restrict__ k_ws,
           __bf16* __restrict__ v_ws)
{
  __shared__ bf16x8 Asm[128 * 4];   // 128 rows x 32 bf16, 16B-granule swizzled
  __shared__ bf16x8 Bsm[128 * 4];
  const int tid = threadIdx.x;
  const int lane = tid & 63, w = tid >> 6;
  const int wr = w >> 1, wc = w & 1;
  const int ag = lane >> 4, lr = lane & 15;
  const int mBase = blockIdx.x * 128;
  const int oBase = blockIdx.y * 128;
  const int which = blockIdx.y >> 3;
  const float* X  = (which == 0) ? Xq : ((which == 1) ? Xk : Xv);
  const float* Wt = W + (size_t)oBase * En;
  __bf16* dst = (which == 0) ? q_ws : ((which == 1) ? k_ws : v_ws);

  f32x4 acc[4][4];
  #pragma unroll
  for (int i = 0; i < 4; ++i)
    #pragma unroll
    for (int j = 0; j < 4; ++j) { f32x4 z = {0.f, 0.f, 0.f, 0.f}; acc[i][j] = z; }

  for (int kk = 0; kk < En; kk += 32) {
    __syncthreads();
    #pragma unroll
    for (int it = 0; it < 2; ++it) {
      int gi = tid + it * 256;            // 512 granules (128 rows x 4)
      int row = gi >> 2, gg = gi & 3;
      const float* pa = X  + (size_t)(mBase + row) * En + kk + gg * 8;
      const float* pb = Wt + (size_t)row * En + kk + gg * 8;
      f32x4 a0 = *reinterpret_cast<const f32x4*>(pa);
      f32x4 a1 = *reinterpret_cast<const f32x4*>(pa + 4);
      f32x4 b0 = *reinterpret_cast<const f32x4*>(pb);
      f32x4 b1 = *reinterpret_cast<const f32x4*>(pb + 4);
      bf16x8 av, bv;
      #pragma unroll
      for (int e = 0; e < 4; ++e) {
        av[e] = (__bf16)a0[e]; av[e + 4] = (__bf16)a1[e];
        bv[e] = (__bf16)b0[e]; bv[e + 4] = (__bf16)b1[e];
      }
      int sg = gg ^ ((row >> 1) & 3);     // bank-decorrelating swizzle (64B rows)
      Asm[row * 4 + sg] = av;
      Bsm[row * 4 + sg] = bv;
    }
    __syncthreads();
    bf16x8 af[4], bfr[4];
    #pragma unroll
    for (int mb = 0; mb < 4; ++mb) {
      int row = wr * 64 + mb * 16 + lr;
      af[mb] = Asm[row * 4 + (ag ^ ((row >> 1) & 3))];
    }
    #pragma unroll
    for (int nb = 0; nb < 4; ++nb) {
      int row = wc * 64 + nb * 16 + lr;
      bfr[nb] = Bsm[row * 4 + (ag ^ ((row >> 1) & 3))];
    }
    #pragma unroll
    for (int mb = 0; mb < 4; ++mb)
      #pragma unroll
      for (int nb = 0; nb < 4; ++nb)
        acc[mb][nb] = MFMA16(af[mb], bfr[nb], acc[mb][nb]);
  }

  #pragma unroll
  for (int nb = 0; nb < 4; ++nb) {
    int oG = oBase + wc * 64 + nb * 16 + lr;
    float bv = bias[oG];
    int oS = oG & (En - 1);
    int h = oS >> 6, d = oS & 63;
    #pragma unroll
    for (int mb = 0; mb < 4; ++mb)
      #pragma unroll
      for (int r = 0; r < 4; ++r) {
        int i = mBase + wr * 64 + mb * 16 + ag * 4 + r;   // D row = (l>>4)*4+r
        int t = i >> 1, b2 = i & 1;                        // i = t*B + b, B=2
        dst[(((size_t)(b2 * Hn + h)) * Tn + t) * Dn + d] =
            (__bf16)(acc[mb][nb][r] + bv);
      }
  }
}

// ---------------------------------------------------------------------------
// Kernel 1b: V [bh, T, D] -> V^T [bh, D, T]  (bf16), LDS tile transpose.
// ---------------------------------------------------------------------------
__global__ __launch_bounds__(256)
void k_transpose_v(const __bf16* __restrict__ v_ws, __bf16* __restrict__ vt_ws)
{
  __shared__ __bf16 tile[64][72];        // +8 pad: column reads bank-rotate
  const int bh = blockIdx.x >> 5;        // 0..31
  const int tt = blockIdx.x & 31;        // 64-row t tile
  const int tid = threadIdx.x;
  const __bf16* src = v_ws + ((size_t)bh * Tn + tt * 64) * Dn;
  #pragma unroll
  for (int it = 0; it < 2; ++it) {
    int gi = tid + it * 256;             // 512 granules (64 x 8)
    int row = gi >> 3, gg = gi & 7;
    *reinterpret_cast<bf16x8*>(&tile[row][gg * 8]) =
        *reinterpret_cast<const bf16x8*>(src + row * Dn + gg * 8);
  }
  __syncthreads();
  __bf16* dst = vt_ws + (size_t)bh * Dn * Tn + tt * 64;
  #pragma unroll
  for (int it = 0; it < 2; ++it) {
    int gi = tid + it * 256;
    int drow = gi >> 3, tg = gi & 7;
    bf16x8 vv;
    #pragma unroll
    for (int e = 0; e < 8; ++e) vv[e] = tile[tg * 8 + e][drow];
    *reinterpret_cast<bf16x8*>(dst + (size_t)drow * Tn + tg * 8) = vv;
  }
}

// ---------------------------------------------------------------------------
// Kernel 2: flash attention per (bh, 64-row q tile). 4 waves x 16 rows.
// Writes ctx bf16 [T,B,E] and per-row (m,l) stats for the avg-weights pass.
// ---------------------------------------------------------------------------
__global__ __launch_bounds__(256)
void k_flash(const __bf16* __restrict__ q_ws, const __bf16* __restrict__ k_ws,
             const __bf16* __restrict__ vt_ws, __bf16* __restrict__ ctx,
             float* __restrict__ stats)
{
  __shared__ bf16x8 k_sm[64 * 8];        // K tile [s][d], XOR-swizzled 128B rows
  __shared__ bf16x8 v_sm[64 * 8];        // V^T tile [d][s]
  __shared__ bf16x8 p_sm[4][16 * 8];     // wave-private P [16 t][64 s]
  const int tid = threadIdx.x;
  const int lane = tid & 63, w = tid >> 6;
  const int ag = lane >> 4, lr = lane & 15;
  const int bh = blockIdx.x >> 5;
  const int qt = blockIdx.x & 31;
  const __bf16* qbase  = q_ws + ((size_t)bh * Tn + qt * 64) * Dn;
  const __bf16* kbase  = k_ws + (size_t)bh * Tn * Dn;
  const __bf16* vtbase = vt_ws + (size_t)bh * Dn * Tn;

  bf16x8 qf[2];   // wave's 16 q rows, k=0..63 (A-frags, loop-invariant)
  {
    const __bf16* qp = qbase + (size_t)(w * 16 + lr) * Dn + ag * 8;
    qf[0] = *reinterpret_cast<const bf16x8*>(qp);
    qf[1] = *reinterpret_cast<const bf16x8*>(qp + 32);
  }

  float m[4], l[4];
  f32x4 acc_o[4];
  #pragma unroll
  for (int r = 0; r < 4; ++r) { m[r] = -INFINITY; l[r] = 0.f; }
  #pragma unroll
  for (int db = 0; db < 4; ++db) { f32x4 z = {0.f,0.f,0.f,0.f}; acc_o[db] = z; }

  for (int st = 0; st < 32; ++st) {
    __syncthreads();
    const __bf16* ks = kbase + (size_t)st * 64 * Dn;   // contiguous 8 KB
    const __bf16* vs = vtbase + st * 64;               // rows stride Tn
    #pragma unroll
    for (int it = 0; it < 2; ++it) {
      int gi = tid + it * 256;
      int row = gi >> 3, gg = gi & 7;
      int sg = gg ^ (row & 7);
      k_sm[row * 8 + sg] = *reinterpret_cast<const bf16x8*>(ks + row * 64 + gg * 8);
      v_sm[row * 8 + sg] = *reinterpret_cast<const bf16x8*>(vs + (size_t)row * Tn + gg * 8);
    }
    __syncthreads();

    // scores: S[t, s] = q . k, t = wave-local rows
    f32x4 sc[4];
    #pragma unroll
    for (int sb = 0; sb < 4; ++sb) {
      int srow = sb * 16 + lr;
      bf16x8 kf0 = k_sm[srow * 8 + (ag ^ (srow & 7))];
      bf16x8 kf1 = k_sm[srow * 8 + ((ag + 4) ^ (srow & 7))];
      f32x4 c = {0.f, 0.f, 0.f, 0.f};
      c = MFMA16(qf[0], kf0, c);
      c = MFMA16(qf[1], kf1, c);
      sc[sb] = c;
    }
    #pragma unroll
    for (int sb = 0; sb < 4; ++sb)
      #pragma unroll
      for (int r = 0; r < 4; ++r) sc[sb][r] *= 0.125f;   // 1/sqrt(64)

    // online softmax: rows live on the 16-lane group (row = ag*4+r)
    float tm[4], rs[4], es[4];
    #pragma unroll
    for (int r = 0; r < 4; ++r)
      tm[r] = fmaxf(fmaxf(sc[0][r], sc[1][r]), fmaxf(sc[2][r], sc[3][r]));
    #pragma unroll
    for (int mask = 1; mask < 16; mask <<= 1)
      #pragma unroll
      for (int r = 0; r < 4; ++r) tm[r] = fmaxf(tm[r], __shfl_xor(tm[r], mask, 64));
    #pragma unroll
    for (int r = 0; r < 4; ++r) {
      float mn = fmaxf(m[r], tm[r]);
      es[r] = __expf(m[r] - mn);      // exp(-inf)=0 on first tile
      m[r] = mn;
      float s0 = 0.f;
      #pragma unroll
      for (int sb = 0; sb < 4; ++sb) {
        float p = __expf(sc[sb][r] - mn);
        sc[sb][r] = p;
        s0 += p;
      }
      rs[r] = s0;
    }
    #pragma unroll
    for (int mask = 1; mask < 16; mask <<= 1)
      #pragma unroll
      for (int r = 0; r < 4; ++r) rs[r] += __shfl_xor(rs[r], mask, 64);
    #pragma unroll
    for (int r = 0; r < 4; ++r) {
      l[r] = l[r] * es[r] + rs[r];
      #pragma unroll
      for (int db = 0; db < 4; ++db) acc_o[db][r] *= es[r];
    }

    // P -> wave-private LDS (bf16), then read back as A-frags
    __bf16* pp = reinterpret_cast<__bf16*>(&p_sm[w][0]);
    #pragma unroll
    for (int sb = 0; sb < 4; ++sb)
      #pragma unroll
      for (int r = 0; r < 4; ++r) {
        int trow = ag * 4 + r;
        int scol = sb * 16 + lr;
        pp[trow * 64 + (((scol >> 3) ^ (trow & 7)) << 3) + (scol & 7)] =
            (__bf16)sc[sb][r];
      }
    bf16x8 pf0, pf1;
    {
      int trow = lr;
      pf0 = p_sm[w][trow * 8 + (ag ^ (trow & 7))];
      pf1 = p_sm[w][trow * 8 + ((ag + 4) ^ (trow & 7))];
    }
    #pragma unroll
    for (int db = 0; db < 4; ++db) {
      int drow = db * 16 + lr;
      bf16x8 v0 = v_sm[drow * 8 + (ag ^ (drow & 7))];
      bf16x8 v1 = v_sm[drow * 8 + ((ag + 4) ^ (drow & 7))];
      acc_o[db] = MFMA16(pf0, v0, acc_o[db]);
      acc_o[db] = MFMA16(pf1, v1, acc_o[db]);
    }
  }

  const int b2 = bh >> 4, h = bh & 15;
  #pragma unroll
  for (int db = 0; db < 4; ++db)
    #pragma unroll
    for (int r = 0; r < 4; ++r) {
      int t = qt * 64 + w * 16 + ag * 4 + r;
      int d = db * 16 + lr;
      ctx[((size_t)t * Bn + b2) * En + h * 64 + d] =
          (__bf16)(acc_o[db][r] / l[r]);
    }
  if (lr == 0) {
    #pragma unroll
    for (int r = 0; r < 4; ++r) {
      int t = qt * 64 + w * 16 + ag * 4 + r;
      size_t si = ((size_t)bh * Tn + t) * 2;
      stats[si] = m[r];
      stats[si + 1] = l[r];
    }
  }
}

// ---------------------------------------------------------------------------
// Kernel 3: avg attention weights. Recompute QK^T with stored (m,l);
// block = (b, 32-row q tile, 512-col s chunk); head-sum held in registers.
// ---------------------------------------------------------------------------
__global__ __launch_bounds__(256)
void k_avgw(const __bf16* __restrict__ q_ws, const __bf16* __restrict__ k_ws,
            const float* __restrict__ stats, float* __restrict__ avg_out)
{
  __shared__ bf16x8 q_sm[32 * 8];
  __shared__ bf16x8 k_sm[64 * 8];
  __shared__ float st_sm[64];
  const int tid = threadIdx.x;
  const int lane = tid & 63, w = tid >> 6;
  const int ag = lane >> 4, lr = lane & 15;
  const int bid = blockIdx.x;            // b*256 + qt*4 + sc
  const int b2 = bid >> 8;
  const int qt = (bid >> 2) & 63;
  const int sc = bid & 3;

  f32x4 avg[8][2];
  #pragma unroll
  for (int i = 0; i < 8; ++i)
    #pragma unroll
    for (int j = 0; j < 2; ++j) { f32x4 z = {0.f,0.f,0.f,0.f}; avg[i][j] = z; }

  for (int h = 0; h < Hn; ++h) {
    const int bh = b2 * Hn + h;
    __syncthreads();
    {
      int row = tid >> 3, gg = tid & 7;  // 256 granules = 32 rows x 8
      const __bf16* qp = q_ws + ((size_t)bh * Tn + qt * 32 + row) * Dn + gg * 8;
      q_sm[row * 8 + (gg ^ (row & 7))] = *reinterpret_cast<const bf16x8*>(qp);
    }
    if (tid < 64)
      st_sm[tid] = stats[((size_t)bh * Tn + qt * 32) * 2 + tid];
    __syncthreads();

    bf16x8 qf[2][2];
    #pragma unroll
    for (int mb = 0; mb < 2; ++mb) {
      int row = mb * 16 + lr;
      qf[mb][0] = q_sm[row * 8 + (ag ^ (row & 7))];
      qf[mb][1] = q_sm[row * 8 + ((ag + 4) ^ (row & 7))];
    }
    float mrow[2][4], rcp[2][4];
    #pragma unroll
    for (int mb = 0; mb < 2; ++mb)
      #pragma unroll
      for (int r = 0; r < 4; ++r) {
        int t = mb * 16 + ag * 4 + r;
        mrow[mb][r] = st_sm[t * 2];
        rcp[mb][r] = 1.0f / (16.0f * st_sm[t * 2 + 1]);
      }

    for (int stt = 0; stt < 8; ++stt) {
      __syncthreads();
      const __bf16* kp0 = k_ws + ((size_t)bh * Tn + sc * 512 + stt * 64) * Dn;
      #pragma unroll
      for (int it = 0; it < 2; ++it) {
        int gi = tid + it * 256;
        int row = gi >> 3, gg = gi & 7;
        k_sm[row * 8 + (gg ^ (row & 7))] =
            *reinterpret_cast<const bf16x8*>(kp0 + row * 64 + gg * 8);
      }
      __syncthreads();
      int srow = w * 16 + lr;            // wave owns 16 s-cols of the tile
      bf16x8 kf0 = k_sm[srow * 8 + (ag ^ (srow & 7))];
      bf16x8 kf1 = k_sm[srow * 8 + ((ag + 4) ^ (srow & 7))];
      #pragma unroll
      for (int mb = 0; mb < 2; ++mb) {
        f32x4 c = {0.f, 0.f, 0.f, 0.f};
        c = MFMA16(qf[mb][0], kf0, c);
        c = MFMA16(qf[mb][1], kf1, c);
        #pragma unroll
        for (int r = 0; r < 4; ++r)
          avg[stt][mb][r] += __expf(c[r] * 0.125f - mrow[mb][r]) * rcp[mb][r];
      }
    }
  }

  #pragma unroll
  for (int stt = 0; stt < 8; ++stt)
    #pragma unroll
    for (int mb = 0; mb < 2; ++mb)
      #pragma unroll
      for (int r = 0; r < 4; ++r) {
        int t = qt * 32 + mb * 16 + ag * 4 + r;
        int s = sc * 512 + stt * 64 + w * 16 + lr;
        avg_out[((size_t)(b2 * Tn + t)) * Tn + s] = avg[stt][mb][r];
      }
}

// ---------------------------------------------------------------------------
// Kernel 4: out projection. out[i,o] = ctx[i,:] . W[o,:] + bias[o], fp32 out.
// ---------------------------------------------------------------------------
__global__ __launch_bounds__(256)
void k_outproj(const __bf16* __restrict__ ctx, const float* __restrict__ W,
               const float* __restrict__ bias, float* __restrict__ out)
{
  __shared__ bf16x8 Asm[128 * 4];
  __shared__ bf16x8 Bsm[128 * 4];
  const int tid = threadIdx.x;
  const int lane = tid & 63, w = tid >> 6;
  const int wr = w >> 1, wc = w & 1;
  const int ag = lane >> 4, lr = lane & 15;
  const int mBase = blockIdx.x * 128;
  const int oBase = blockIdx.y * 128;

  f32x4 acc[4][4];
  #pragma unroll
  for (int i = 0; i < 4; ++i)
    #pragma unroll
    for (int j = 0; j < 4; ++j) { f32x4 z = {0.f,0.f,0.f,0.f}; acc[i][j] = z; }

  for (int kk = 0; kk < En; kk += 32) {
    __syncthreads();
    #pragma unroll
    for (int it = 0; it < 2; ++it) {
      int gi = tid + it * 256;
      int row = gi >> 2, gg = gi & 3;
      bf16x8 av = *reinterpret_cast<const bf16x8*>(
          ctx + (size_t)(mBase + row) * En + kk + gg * 8);
      const float* pb = W + (size_t)(oBase + row) * En + kk + gg * 8;
      f32x4 b0 = *reinterpret_cast<const f32x4*>(pb);
      f32x4 b1 = *reinterpret_cast<const f32x4*>(pb + 4);
      bf16x8 bv;
      #pragma unroll
      for (int e = 0; e < 4; ++e) { bv[e] = (__bf16)b0[e]; bv[e + 4] = (__bf16)b1[e]; }
      int sg = gg ^ ((row >> 1) & 3);
      Asm[row * 4 + sg] = av;
      Bsm[row * 4 + sg] = bv;
    }
    __syncthreads();
    bf16x8 af[4], bfr[4];
    #pragma unroll
    for (int mb = 0; mb < 4; ++mb) {
      int row = wr * 64 + mb * 16 + lr;
      af[mb] = Asm[row * 4 + (ag ^ ((row >> 1) & 3))];
    }
    #pragma unroll
    for (int nb = 0; nb < 4; ++nb) {
      int row = wc * 64 + nb * 16 + lr;
      bfr[nb] = Bsm[row * 4 + (ag ^ ((row >> 1) & 3))];
    }
    #pragma unroll
    for (int mb = 0; mb < 4; ++mb)
      #pragma unroll
      for (int nb = 0; nb < 4; ++nb)
        acc[mb][nb] = MFMA16(af[mb], bfr[nb], acc[mb][nb]);
  }

  #pragma unroll
  for (int nb = 0; nb < 4; ++nb) {
    int o = oBase + wc * 64 + nb * 16 + lr;
    float bv = bias[o];
    #pragma unroll
    for (int mb = 0; mb < 4; ++mb)
      #pragma unroll
      for (int r = 0; r < 4; ++r) {
        int i = mBase + wr * 64 + mb * 16 + ag * 4 + r;
        out[(size_t)i * En + o] = acc[mb][nb][r] + bv;
      }
  }
}

// ---------------------------------------------------------------------------
extern "C" void kernel_launch(void* const* d_in, const int* in_sizes, int n_in,
                              void* d_out, int out_size, void* d_ws, size_t ws_size,
                              hipStream_t stream)
{
  (void)in_sizes; (void)n_in; (void)out_size; (void)ws_size;
  const float* query = (const float*)d_in[0];
  const float* key   = (const float*)d_in[1];
  const float* value = (const float*)d_in[2];
  const float* in_w  = (const float*)d_in[3];
  const float* in_b  = (const float*)d_in[4];
  const float* out_w = (const float*)d_in[5];
  const float* out_b = (const float*)d_in[6];

  float* attn_out = (float*)d_out;                                 // [T,B,E]
  float* avg_out  = (float*)d_out + (size_t)Tn * Bn * En;          // [B,T,S]

  char* ws = (char*)d_ws;
  __bf16* q_ws  = (__bf16*)(ws);                    // [B,H,T,D] bf16, 8 MB
  __bf16* k_ws  = (__bf16*)(ws + (8u  << 20));      // 8 MB
  __bf16* v_ws  = (__bf16*)(ws + (16u << 20));      // 8 MB
  __bf16* vt_ws = (__bf16*)(ws + (24u << 20));      // [B,H,D,T] 8 MB
  __bf16* ctx   = (__bf16*)(ws + (32u << 20));      // [T,B,E] 8 MB
  float*  stats = (float*)(ws + (40u << 20));       // [B,H,T,2] 512 KB

  k_qkv<<<dim3(32, 24), 256, 0, stream>>>(query, key, value, in_w, in_b,
                                          q_ws, k_ws, v_ws);
  k_transpose_v<<<1024, 256, 0, stream>>>(v_ws, vt_ws);
  k_flash<<<1024, 256, 0, stream>>>(q_ws, k_ws, vt_ws, ctx, stats);
  k_avgw<<<512, 256, 0, stream>>>(q_ws, k_ws, stats, avg_out);
  k_outproj<<<dim3(32, 8), 256, 0, stream>>>(ctx, out_w, out_b, attn_out);
}

// Round 2
// 289.377 us; speedup vs baseline: 1.1588x; 1.1588x over previous
//
#include <hip/hip_runtime.h>
#include <hip/hip_bf16.h>

typedef float  f32x2  __attribute__((ext_vector_type(2)));
typedef float  f32x4  __attribute__((ext_vector_type(4)));
typedef float  f32x16 __attribute__((ext_vector_type(16)));
typedef __bf16 bf16x8 __attribute__((ext_vector_type(8)));

#define MFMA16(A,B,C) __builtin_amdgcn_mfma_f32_16x16x32_bf16((A),(B),(C),0,0,0)
#define MFMA32(A,B,C) __builtin_amdgcn_mfma_f32_32x32x16_bf16((A),(B),(C),0,0,0)

static constexpr int Tn = 2048, Bn = 2, En = 1024, Hn = 16, Dn = 64;

static __device__ __forceinline__ unsigned pack2(float a, float b) {
  union { __bf16 h[2]; unsigned u; } un;
  un.h[0] = (__bf16)a; un.h[1] = (__bf16)b;
  return un.u;
}

// ---------------------------------------------------------------------------
// Kernel 1: fused QKV in-projection.  C[i,o] = X[i,:] . W[o,:] + bias[o]
// Q rows are pre-scaled by 1/sqrt(D) so flash/avgw skip the score scale.
// ---------------------------------------------------------------------------
__global__ __launch_bounds__(256)
void k_qkv(const float* __restrict__ Xq, const float* __restrict__ Xk,
           const float* __restrict__ Xv, const float* __restrict__ W,
           const float* __restrict__ bias,
           __bf16* __restrict__ q_ws, __bf16* __restrict__ k_ws,
           __bf16* __restrict__ v_ws)
{
  __shared__ bf16x8 Asm[128 * 4];
  __shared__ bf16x8 Bsm[128 * 4];
  const int tid = threadIdx.x;
  const int lane = tid & 63, w = tid >> 6;
  const int wr = w >> 1, wc = w & 1;
  const int ag = lane >> 4, lr = lane & 15;
  const int mBase = blockIdx.x * 128;
  const int oBase = blockIdx.y * 128;
  const int which = blockIdx.y >> 3;
  const float* X  = (which == 0) ? Xq : ((which == 1) ? Xk : Xv);
  const float* Wt = W + (size_t)oBase * En;
  __bf16* dst = (which == 0) ? q_ws : ((which == 1) ? k_ws : v_ws);
  const float oscale = (which == 0) ? 0.125f : 1.0f;

  f32x4 acc[4][4];
  #pragma unroll
  for (int i = 0; i < 4; ++i)
    #pragma unroll
    for (int j = 0; j < 4; ++j) { f32x4 z = {0.f, 0.f, 0.f, 0.f}; acc[i][j] = z; }

  for (int kk = 0; kk < En; kk += 32) {
    __syncthreads();
    #pragma unroll
    for (int it = 0; it < 2; ++it) {
      int gi = tid + it * 256;
      int row = gi >> 2, gg = gi & 3;
      const float* pa = X  + (size_t)(mBase + row) * En + kk + gg * 8;
      const float* pb = Wt + (size_t)row * En + kk + gg * 8;
      f32x4 a0 = *reinterpret_cast<const f32x4*>(pa);
      f32x4 a1 = *reinterpret_cast<const f32x4*>(pa + 4);
      f32x4 b0 = *reinterpret_cast<const f32x4*>(pb);
      f32x4 b1 = *reinterpret_cast<const f32x4*>(pb + 4);
      bf16x8 av, bv;
      #pragma unroll
      for (int e = 0; e < 4; ++e) {
        av[e] = (__bf16)a0[e]; av[e + 4] = (__bf16)a1[e];
        bv[e] = (__bf16)b0[e]; bv[e + 4] = (__bf16)b1[e];
      }
      int sg = gg ^ ((row >> 1) & 3);
      Asm[row * 4 + sg] = av;
      Bsm[row * 4 + sg] = bv;
    }
    __syncthreads();
    bf16x8 af[4], bfr[4];
    #pragma unroll
    for (int mb = 0; mb < 4; ++mb) {
      int row = wr * 64 + mb * 16 + lr;
      af[mb] = Asm[row * 4 + (ag ^ ((row >> 1) & 3))];
    }
    #pragma unroll
    for (int nb = 0; nb < 4; ++nb) {
      int row = wc * 64 + nb * 16 + lr;
      bfr[nb] = Bsm[row * 4 + (ag ^ ((row >> 1) & 3))];
    }
    #pragma unroll
    for (int mb = 0; mb < 4; ++mb)
      #pragma unroll
      for (int nb = 0; nb < 4; ++nb)
        acc[mb][nb] = MFMA16(af[mb], bfr[nb], acc[mb][nb]);
  }

  #pragma unroll
  for (int nb = 0; nb < 4; ++nb) {
    int oG = oBase + wc * 64 + nb * 16 + lr;
    float bv = bias[oG];
    int oS = oG & (En - 1);
    int h = oS >> 6, d = oS & 63;
    #pragma unroll
    for (int mb = 0; mb < 4; ++mb)
      #pragma unroll
      for (int r = 0; r < 4; ++r) {
        int i = mBase + wr * 64 + mb * 16 + ag * 4 + r;
        int t = i >> 1, b2 = i & 1;
        dst[(((size_t)(b2 * Hn + h)) * Tn + t) * Dn + d] =
            (__bf16)((acc[mb][nb][r] + bv) * oscale);
      }
  }
}

// ---------------------------------------------------------------------------
// Kernel 1b: V [bh, T, D] -> V^T [bh, D, T]  (bf16), LDS tile transpose.
// ---------------------------------------------------------------------------
__global__ __launch_bounds__(256)
void k_transpose_v(const __bf16* __restrict__ v_ws, __bf16* __restrict__ vt_ws)
{
  __shared__ __bf16 tile[64][72];
  const int bh = blockIdx.x >> 5;
  const int tt = blockIdx.x & 31;
  const int tid = threadIdx.x;
  const __bf16* src = v_ws + ((size_t)bh * Tn + tt * 64) * Dn;
  #pragma unroll
  for (int it = 0; it < 2; ++it) {
    int gi = tid + it * 256;
    int row = gi >> 3, gg = gi & 7;
    *reinterpret_cast<bf16x8*>(&tile[row][gg * 8]) =
        *reinterpret_cast<const bf16x8*>(src + row * Dn + gg * 8);
  }
  __syncthreads();
  __bf16* dst = vt_ws + (size_t)bh * Dn * Tn + tt * 64;
  #pragma unroll
  for (int it = 0; it < 2; ++it) {
    int gi = tid + it * 256;
    int drow = gi >> 3, tg = gi & 7;
    bf16x8 vv;
    #pragma unroll
    for (int e = 0; e < 8; ++e) vv[e] = tile[tg * 8 + e][drow];
    *reinterpret_cast<bf16x8*>(dst + (size_t)drow * Tn + tg * 8) = vv;
  }
}

// ---------------------------------------------------------------------------
// Kernel 2: flash attention, swapped-operand 32x32 MFMA structure.
// 4 waves x 32 q-rows (QBLK=128); KVBLK=64, K/V^T in XOR-swizzled LDS.
// Scores S = mfma(A=K, B=Q): lane holds col t=lane&31, rows s in 16 regs.
// Softmax in-register; P->A-frag via pack2 + shfl_xor(32).
// ---------------------------------------------------------------------------
__global__ __launch_bounds__(256, 2)
void k_flash(const __bf16* __restrict__ q_ws, const __bf16* __restrict__ k_ws,
             const __bf16* __restrict__ vt_ws, __bf16* __restrict__ ctx,
             float* __restrict__ stats)
{
  __shared__ __align__(16) char k_sm[8192];   // [64 s][64 d], 128B rows, swizzled
  __shared__ __align__(16) char v_sm[8192];   // [64 d][64 s], 128B rows, swizzled
  __shared__ __align__(16) float es_sm[4][32];

  const int tid = threadIdx.x;
  const int lane = tid & 63, w = tid >> 6;
  const int tl = lane & 31, hi = lane >> 5;
  const int bh = blockIdx.x >> 4;
  const int qt = blockIdx.x & 15;
  const int t0w = qt * 128 + w * 32;

  const __bf16* kbase  = k_ws + (size_t)bh * Tn * Dn;
  const __bf16* vtbase = vt_ws + (size_t)bh * Dn * Tn;

  // Q B-frags: lane holds Q[t0w+tl][c*16 + hi*8 + j]
  bf16x8 qf[4];
  {
    const __bf16* qrow = q_ws + ((size_t)bh * Tn + t0w + tl) * Dn + hi * 8;
    #pragma unroll
    for (int c = 0; c < 4; ++c)
      qf[c] = *reinterpret_cast<const bf16x8*>(qrow + c * 16);
  }

  f32x16 accO0, accO1;
  #pragma unroll
  for (int i = 0; i < 16; ++i) { accO0[i] = 0.f; accO1[i] = 0.f; }
  float m_run = -INFINITY, l_run = 0.f;

  // staging: thread owns granules (row r0, slot s0) and (row r0+32, slot s0)
  const int r0 = tid >> 3, s0 = tid & 7;
  const int ldso = ((s0 ^ (r0 & 7)) << 4);
  const int ko0 = r0 * 128 + ldso, ko1 = ko0 + 32 * 128;

  bf16x8 rk0 = *(const bf16x8*)(kbase + r0 * 64 + s0 * 8);
  bf16x8 rk1 = *(const bf16x8*)(kbase + (r0 + 32) * 64 + s0 * 8);
  bf16x8 rv0 = *(const bf16x8*)(vtbase + (size_t)r0 * Tn + s0 * 8);
  bf16x8 rv1 = *(const bf16x8*)(vtbase + (size_t)(r0 + 32) * Tn + s0 * 8);

  for (int st = 0; st < 32; ++st) {
    __syncthreads();
    *(bf16x8*)(k_sm + ko0) = rk0;
    *(bf16x8*)(k_sm + ko1) = rk1;
    *(bf16x8*)(v_sm + ko0) = rv0;
    *(bf16x8*)(v_sm + ko1) = rv1;
    __syncthreads();
    if (st + 1 < 32) {   // issue next tile's loads; land during compute (T14)
      const __bf16* kn = kbase + (size_t)(st + 1) * 64 * Dn;
      const __bf16* vn = vtbase + (st + 1) * 64;
      rk0 = *(const bf16x8*)(kn + r0 * 64 + s0 * 8);
      rk1 = *(const bf16x8*)(kn + (r0 + 32) * 64 + s0 * 8);
      rv0 = *(const bf16x8*)(vn + (size_t)r0 * Tn + s0 * 8);
      rv1 = *(const bf16x8*)(vn + (size_t)(r0 + 32) * Tn + s0 * 8);
    }

    // QK^T (swapped): sc{0,1}[reg] = S[s = ss*32 + 8*(reg>>2)+4*hi+(reg&3)][t]
    f32x16 sc0, sc1;
    #pragma unroll
    for (int i = 0; i < 16; ++i) { sc0[i] = 0.f; sc1[i] = 0.f; }
    const char* kr0 = k_sm + tl * 128;
    const char* kr1 = k_sm + (32 + tl) * 128;
    #pragma unroll
    for (int c = 0; c < 4; ++c) {
      const int off = (((2 * c + hi) ^ (tl & 7)) << 4);
      sc0 = MFMA32(*(const bf16x8*)(kr0 + off), qf[c], sc0);
      sc1 = MFMA32(*(const bf16x8*)(kr1 + off), qf[c], sc1);
    }

    // online softmax over 64 s (scores pre-scaled via Q)
    float mx[8];
    #pragma unroll
    for (int i = 0; i < 8; ++i)
      mx[i] = fmaxf(fmaxf(sc0[i], sc0[i + 8]), fmaxf(sc1[i], sc1[i + 8]));
    float tm = fmaxf(fmaxf(fmaxf(mx[0], mx[1]), fmaxf(mx[2], mx[3])),
                     fmaxf(fmaxf(mx[4], mx[5]), fmaxf(mx[6], mx[7])));
    tm = fmaxf(tm, __shfl_xor(tm, 32, 64));
    const float mn = fmaxf(m_run, tm);
    const float es = __expf(m_run - mn);
    m_run = mn;
    #pragma unroll
    for (int i = 0; i < 16; ++i) {
      sc0[i] = __expf(sc0[i] - mn);
      sc1[i] = __expf(sc1[i] - mn);
    }
    float p0s = 0.f, p1s = 0.f, p2s = 0.f, p3s = 0.f;
    #pragma unroll
    for (int i = 0; i < 16; i += 4) {
      p0s += sc0[i]     + sc1[i];
      p1s += sc0[i + 1] + sc1[i + 1];
      p2s += sc0[i + 2] + sc1[i + 2];
      p3s += sc0[i + 3] + sc1[i + 3];
    }
    float rs = (p0s + p1s) + (p2s + p3s);
    rs += __shfl_xor(rs, 32, 64);
    l_run = l_run * es + rs;

    // redistribute es[t] to O's row-in-reg pattern via wave-private LDS
    es_sm[w][tl] = es;
    f32x4 esr[4];
    #pragma unroll
    for (int q = 0; q < 4; ++q)
      esr[q] = *(const f32x4*)&es_sm[w][8 * q + 4 * hi];
    #pragma unroll
    for (int q = 0; q < 4; ++q)
      #pragma unroll
      for (int rr = 0; rr < 4; ++rr) {
        accO0[q * 4 + rr] *= esr[q][rr];
        accO1[q * 4 + rr] *= esr[q][rr];
      }

    // P -> bf16 A-frags: frag(c)[j] = P[t][c*16 + hi*8 + j]
    unsigned wA0[4], wB0[4], wA1[4], wB1[4];
    #pragma unroll
    for (int g = 0; g < 4; ++g) {
      wA0[g] = pack2(sc0[4 * g],     sc0[4 * g + 1]);
      wB0[g] = pack2(sc0[4 * g + 2], sc0[4 * g + 3]);
      wA1[g] = pack2(sc1[4 * g],     sc1[4 * g + 1]);
      wB1[g] = pack2(sc1[4 * g + 2], sc1[4 * g + 3]);
    }
    bf16x8 pa[2][2];
    #pragma unroll
    for (int sb = 0; sb < 2; ++sb) {
      const unsigned* WA = sb ? wA1 : wA0;
      const unsigned* WB = sb ? wB1 : wB0;
      #pragma unroll
      for (int c = 0; c < 2; ++c) {
        unsigned a0 = WA[2 * c], a1 = WA[2 * c + 1];
        unsigned b0 = WB[2 * c], b1 = WB[2 * c + 1];
        unsigned xa0 = __shfl_xor(a0, 32, 64);
        unsigned xa1 = __shfl_xor(a1, 32, 64);
        unsigned xb0 = __shfl_xor(b0, 32, 64);
        unsigned xb1 = __shfl_xor(b1, 32, 64);
        union { unsigned u[4]; bf16x8 v; } uu;
        uu.u[0] = hi ? xa1 : a0;   // lo half, word0 (u=0,1)
        uu.u[1] = hi ? xb1 : b0;   // lo half, word1 (u=2,3)
        uu.u[2] = hi ? a1 : xa0;   // hi half, word0 (u=4,5)
        uu.u[3] = hi ? b1 : xb0;   // hi half, word1 (u=6,7)
        pa[sb][c] = uu.v;
      }
    }

    // PV: O[t][d] += P . V, B-frag from V^T tile
    const char* vr0 = v_sm + tl * 128;
    const char* vr1 = v_sm + (32 + tl) * 128;
    #pragma unroll
    for (int sb = 0; sb < 2; ++sb)
      #pragma unroll
      for (int c = 0; c < 2; ++c) {
        const int off = (((sb * 4 + c * 2 + hi) ^ (tl & 7)) << 4);
        accO0 = MFMA32(pa[sb][c], *(const bf16x8*)(vr0 + off), accO0);
        accO1 = MFMA32(pa[sb][c], *(const bf16x8*)(vr1 + off), accO1);
      }
  }

  // epilogue
  const float linv = 1.0f / l_run;
  es_sm[w][tl] = linv;
  f32x4 lr[4];
  #pragma unroll
  for (int q = 0; q < 4; ++q)
    lr[q] = *(const f32x4*)&es_sm[w][8 * q + 4 * hi];
  const int b2 = bh >> 4, h = bh & 15;
  #pragma unroll
  for (int q = 0; q < 4; ++q)
    #pragma unroll
    for (int rr = 0; rr < 4; ++rr) {
      const int t = t0w + 8 * q + 4 * hi + rr;
      __bf16* cp = ctx + ((size_t)t * Bn + b2) * En + h * 64 + tl;
      cp[0]  = (__bf16)(accO0[q * 4 + rr] * lr[q][rr]);
      cp[32] = (__bf16)(accO1[q * 4 + rr] * lr[q][rr]);
    }
  if (hi == 0) {
    const int t = t0w + tl;
    f32x2 stv; stv[0] = m_run; stv[1] = l_run;
    *reinterpret_cast<f32x2*>(&stats[((size_t)bh * Tn + t) * 2]) = stv;
  }
}

// ---------------------------------------------------------------------------
// Kernel 3: avg attention weights (recompute QK^T with stored m,l).
// NOTE: Q is pre-scaled, so no 0.125 here.
// ---------------------------------------------------------------------------
__global__ __launch_bounds__(256)
void k_avgw(const __bf16* __restrict__ q_ws, const __bf16* __restrict__ k_ws,
            const float* __restrict__ stats, float* __restrict__ avg_out)
{
  __shared__ bf16x8 q_sm[32 * 8];
  __shared__ bf16x8 k_sm[64 * 8];
  __shared__ float st_sm[64];
  const int tid = threadIdx.x;
  const int lane = tid & 63, w = tid >> 6;
  const int ag = lane >> 4, lr = lane & 15;
  const int bid = blockIdx.x;
  const int b2 = bid >> 8;
  const int qt = (bid >> 2) & 63;
  const int sc = bid & 3;

  f32x4 avg[8][2];
  #pragma unroll
  for (int i = 0; i < 8; ++i)
    #pragma unroll
    for (int j = 0; j < 2; ++j) { f32x4 z = {0.f,0.f,0.f,0.f}; avg[i][j] = z; }

  for (int h = 0; h < Hn; ++h) {
    const int bh = b2 * Hn + h;
    __syncthreads();
    {
      int row = tid >> 3, gg = tid & 7;
      const __bf16* qp = q_ws + ((size_t)bh * Tn + qt * 32 + row) * Dn + gg * 8;
      q_sm[row * 8 + (gg ^ (row & 7))] = *reinterpret_cast<const bf16x8*>(qp);
    }
    if (tid < 64)
      st_sm[tid] = stats[((size_t)bh * Tn + qt * 32) * 2 + tid];
    __syncthreads();

    bf16x8 qf[2][2];
    #pragma unroll
    for (int mb = 0; mb < 2; ++mb) {
      int row = mb * 16 + lr;
      qf[mb][0] = q_sm[row * 8 + (ag ^ (row & 7))];
      qf[mb][1] = q_sm[row * 8 + ((ag + 4) ^ (row & 7))];
    }
    float mrow[2][4], rcp[2][4];
    #pragma unroll
    for (int mb = 0; mb < 2; ++mb)
      #pragma unroll
      for (int r = 0; r < 4; ++r) {
        int t = mb * 16 + ag * 4 + r;
        mrow[mb][r] = st_sm[t * 2];
        rcp[mb][r] = 1.0f / (16.0f * st_sm[t * 2 + 1]);
      }

    for (int stt = 0; stt < 8; ++stt) {
      __syncthreads();
      const __bf16* kp0 = k_ws + ((size_t)bh * Tn + sc * 512 + stt * 64) * Dn;
      #pragma unroll
      for (int it = 0; it < 2; ++it) {
        int gi = tid + it * 256;
        int row = gi >> 3, gg = gi & 7;
        k_sm[row * 8 + (gg ^ (row & 7))] =
            *reinterpret_cast<const bf16x8*>(kp0 + row * 64 + gg * 8);
      }
      __syncthreads();
      int srow = w * 16 + lr;
      bf16x8 kf0 = k_sm[srow * 8 + (ag ^ (srow & 7))];
      bf16x8 kf1 = k_sm[srow * 8 + ((ag + 4) ^ (srow & 7))];
      #pragma unroll
      for (int mb = 0; mb < 2; ++mb) {
        f32x4 c = {0.f, 0.f, 0.f, 0.f};
        c = MFMA16(qf[mb][0], kf0, c);
        c = MFMA16(qf[mb][1], kf1, c);
        #pragma unroll
        for (int r = 0; r < 4; ++r)
          avg[stt][mb][r] += __expf(c[r] - mrow[mb][r]) * rcp[mb][r];
      }
    }
  }

  #pragma unroll
  for (int stt = 0; stt < 8; ++stt)
    #pragma unroll
    for (int mb = 0; mb < 2; ++mb)
      #pragma unroll
      for (int r = 0; r < 4; ++r) {
        int t = qt * 32 + mb * 16 + ag * 4 + r;
        int s = sc * 512 + stt * 64 + w * 16 + lr;
        avg_out[((size_t)(b2 * Tn + t)) * Tn + s] = avg[stt][mb][r];
      }
}

// ---------------------------------------------------------------------------
// Kernel 4: out projection. out[i,o] = ctx[i,:] . W[o,:] + bias[o], fp32 out.
// ---------------------------------------------------------------------------
__global__ __launch_bounds__(256)
void k_outproj(const __bf16* __restrict__ ctx, const float* __restrict__ W,
               const float* __restrict__ bias, float* __restrict__ out)
{
  __shared__ bf16x8 Asm[128 * 4];
  __shared__ bf16x8 Bsm[128 * 4];
  const int tid = threadIdx.x;
  const int lane = tid & 63, w = tid >> 6;
  const int wr = w >> 1, wc = w & 1;
  const int ag = lane >> 4, lr = lane & 15;
  const int mBase = blockIdx.x * 128;
  const int oBase = blockIdx.y * 128;

  f32x4 acc[4][4];
  #pragma unroll
  for (int i = 0; i < 4; ++i)
    #pragma unroll
    for (int j = 0; j < 4; ++j) { f32x4 z = {0.f,0.f,0.f,0.f}; acc[i][j] = z; }

  for (int kk = 0; kk < En; kk += 32) {
    __syncthreads();
    #pragma unroll
    for (int it = 0; it < 2; ++it) {
      int gi = tid + it * 256;
      int row = gi >> 2, gg = gi & 3;
      bf16x8 av = *reinterpret_cast<const bf16x8*>(
          ctx + (size_t)(mBase + row) * En + kk + gg * 8);
      const float* pb = W + (size_t)(oBase + row) * En + kk + gg * 8;
      f32x4 b0 = *reinterpret_cast<const f32x4*>(pb);
      f32x4 b1 = *reinterpret_cast<const f32x4*>(pb + 4);
      bf16x8 bv;
      #pragma unroll
      for (int e = 0; e < 4; ++e) { bv[e] = (__bf16)b0[e]; bv[e + 4] = (__bf16)b1[e]; }
      int sg = gg ^ ((row >> 1) & 3);
      Asm[row * 4 + sg] = av;
      Bsm[row * 4 + sg] = bv;
    }
    __syncthreads();
    bf16x8 af[4], bfr[4];
    #pragma unroll
    for (int mb = 0; mb < 4; ++mb) {
      int row = wr * 64 + mb * 16 + lr;
      af[mb] = Asm[row * 4 + (ag ^ ((row >> 1) & 3))];
    }
    #pragma unroll
    for (int nb = 0; nb < 4; ++nb) {
      int row = wc * 64 + nb * 16 + lr;
      bfr[nb] = Bsm[row * 4 + (ag ^ ((row >> 1) & 3))];
    }
    #pragma unroll
    for (int mb = 0; mb < 4; ++mb)
      #pragma unroll
      for (int nb = 0; nb < 4; ++nb)
        acc[mb][nb] = MFMA16(af[mb], bfr[nb], acc[mb][nb]);
  }

  #pragma unroll
  for (int nb = 0; nb < 4; ++nb) {
    int o = oBase + wc * 64 + nb * 16 + lr;
    float bv = bias[o];
    #pragma unroll
    for (int mb = 0; mb < 4; ++mb)
      #pragma unroll
      for (int r = 0; r < 4; ++r) {
        int i = mBase + wr * 64 + mb * 16 + ag * 4 + r;
        out[(size_t)i * En + o] = acc[mb][nb][r] + bv;
      }
  }
}

// ---------------------------------------------------------------------------
extern "C" void kernel_launch(void* const* d_in, const int* in_sizes, int n_in,
                              void* d_out, int out_size, void* d_ws, size_t ws_size,
                              hipStream_t stream)
{
  (void)in_sizes; (void)n_in; (void)out_size; (void)ws_size;
  const float* query = (const float*)d_in[0];
  const float* key   = (const float*)d_in[1];
  const float* value = (const float*)d_in[2];
  const float* in_w  = (const float*)d_in[3];
  const float* in_b  = (const float*)d_in[4];
  const float* out_w = (const float*)d_in[5];
  const float* out_b = (const float*)d_in[6];

  float* attn_out = (float*)d_out;                                 // [T,B,E]
  float* avg_out  = (float*)d_out + (size_t)Tn * Bn * En;          // [B,T,S]

  char* ws = (char*)d_ws;
  __bf16* q_ws  = (__bf16*)(ws);                    // [B,H,T,D] bf16, 8 MB
  __bf16* k_ws  = (__bf16*)(ws + (8u  << 20));      // 8 MB
  __bf16* v_ws  = (__bf16*)(ws + (16u << 20));      // 8 MB
  __bf16* vt_ws = (__bf16*)(ws + (24u << 20));      // [B,H,D,T] 8 MB
  __bf16* ctx   = (__bf16*)(ws + (32u << 20));      // [T,B,E] 8 MB
  float*  stats = (float*)(ws + (40u << 20));       // [B,H,T,2] 512 KB

  k_qkv<<<dim3(32, 24), 256, 0, stream>>>(query, key, value, in_w, in_b,
                                          q_ws, k_ws, v_ws);
  k_transpose_v<<<1024, 256, 0, stream>>>(v_ws, vt_ws);
  k_flash<<<512, 256, 0, stream>>>(q_ws, k_ws, vt_ws, ctx, stats);
  k_avgw<<<512, 256, 0, stream>>>(q_ws, k_ws, stats, avg_out);
  k_outproj<<<dim3(32, 8), 256, 0, stream>>>(ctx, out_w, out_b, attn_out);
}

// Round 3
// 207.686 us; speedup vs baseline: 1.6146x; 1.3933x over previous
//
#include <hip/hip_runtime.h>
#include <hip/hip_bf16.h>

typedef float  f32x2  __attribute__((ext_vector_type(2)));
typedef float  f32x4  __attribute__((ext_vector_type(4)));
typedef float  f32x16 __attribute__((ext_vector_type(16)));
typedef __bf16 bf16x8 __attribute__((ext_vector_type(8)));

#define MFMA16(A,B,C) __builtin_amdgcn_mfma_f32_16x16x32_bf16((A),(B),(C),0,0,0)
#define MFMA32(A,B,C) __builtin_amdgcn_mfma_f32_32x32x16_bf16((A),(B),(C),0,0,0)
#define EXP2(x) __builtin_amdgcn_exp2f(x)
#define LOG2(x) __builtin_amdgcn_logf(x)

static constexpr int Tn = 2048, Bn = 2, En = 1024, Hn = 16, Dn = 64;
// Q is pre-scaled by (1/sqrt(D)) * log2(e): all score math is in log2 domain.
static constexpr float kQScale = 0.125f * 1.4426950408889634f;

static __device__ __forceinline__ unsigned pack2(float a, float b) {
  union { __bf16 h[2]; unsigned u; } un;
  un.h[0] = (__bf16)a; un.h[1] = (__bf16)b;
  return un.u;
}

// ---------------------------------------------------------------------------
// Kernel 1: fused QKV in-projection.  C[i,o] = X[i,:] . W[o,:] + bias[o]
// ---------------------------------------------------------------------------
__global__ __launch_bounds__(256)
void k_qkv(const float* __restrict__ Xq, const float* __restrict__ Xk,
           const float* __restrict__ Xv, const float* __restrict__ W,
           const float* __restrict__ bias,
           __bf16* __restrict__ q_ws, __bf16* __restrict__ k_ws,
           __bf16* __restrict__ v_ws)
{
  __shared__ bf16x8 Asm[128 * 4];
  __shared__ bf16x8 Bsm[128 * 4];
  const int tid = threadIdx.x;
  const int lane = tid & 63, w = tid >> 6;
  const int wr = w >> 1, wc = w & 1;
  const int ag = lane >> 4, lr = lane & 15;
  const int mBase = blockIdx.x * 128;
  const int oBase = blockIdx.y * 128;
  const int which = blockIdx.y >> 3;
  const float* X  = (which == 0) ? Xq : ((which == 1) ? Xk : Xv);
  const float* Wt = W + (size_t)oBase * En;
  __bf16* dst = (which == 0) ? q_ws : ((which == 1) ? k_ws : v_ws);
  const float oscale = (which == 0) ? kQScale : 1.0f;

  f32x4 acc[4][4];
  #pragma unroll
  for (int i = 0; i < 4; ++i)
    #pragma unroll
    for (int j = 0; j < 4; ++j) { f32x4 z = {0.f, 0.f, 0.f, 0.f}; acc[i][j] = z; }

  for (int kk = 0; kk < En; kk += 32) {
    __syncthreads();
    #pragma unroll
    for (int it = 0; it < 2; ++it) {
      int gi = tid + it * 256;
      int row = gi >> 2, gg = gi & 3;
      const float* pa = X  + (size_t)(mBase + row) * En + kk + gg * 8;
      const float* pb = Wt + (size_t)row * En + kk + gg * 8;
      f32x4 a0 = *reinterpret_cast<const f32x4*>(pa);
      f32x4 a1 = *reinterpret_cast<const f32x4*>(pa + 4);
      f32x4 b0 = *reinterpret_cast<const f32x4*>(pb);
      f32x4 b1 = *reinterpret_cast<const f32x4*>(pb + 4);
      bf16x8 av, bv;
      #pragma unroll
      for (int e = 0; e < 4; ++e) {
        av[e] = (__bf16)a0[e]; av[e + 4] = (__bf16)a1[e];
        bv[e] = (__bf16)b0[e]; bv[e + 4] = (__bf16)b1[e];
      }
      int sg = gg ^ ((row >> 1) & 3);
      Asm[row * 4 + sg] = av;
      Bsm[row * 4 + sg] = bv;
    }
    __syncthreads();
    bf16x8 af[4], bfr[4];
    #pragma unroll
    for (int mb = 0; mb < 4; ++mb) {
      int row = wr * 64 + mb * 16 + lr;
      af[mb] = Asm[row * 4 + (ag ^ ((row >> 1) & 3))];
    }
    #pragma unroll
    for (int nb = 0; nb < 4; ++nb) {
      int row = wc * 64 + nb * 16 + lr;
      bfr[nb] = Bsm[row * 4 + (ag ^ ((row >> 1) & 3))];
    }
    #pragma unroll
    for (int mb = 0; mb < 4; ++mb)
      #pragma unroll
      for (int nb = 0; nb < 4; ++nb)
        acc[mb][nb] = MFMA16(af[mb], bfr[nb], acc[mb][nb]);
  }

  #pragma unroll
  for (int nb = 0; nb < 4; ++nb) {
    int oG = oBase + wc * 64 + nb * 16 + lr;
    float bv = bias[oG];
    int oS = oG & (En - 1);
    int h = oS >> 6, d = oS & 63;
    #pragma unroll
    for (int mb = 0; mb < 4; ++mb)
      #pragma unroll
      for (int r = 0; r < 4; ++r) {
        int i = mBase + wr * 64 + mb * 16 + ag * 4 + r;
        int t = i >> 1, b2 = i & 1;
        dst[(((size_t)(b2 * Hn + h)) * Tn + t) * Dn + d] =
            (__bf16)((acc[mb][nb][r] + bv) * oscale);
      }
  }
}

// ---------------------------------------------------------------------------
// Kernel 1b: V [bh, T, D] -> V^T [bh, D, T]  (bf16), LDS tile transpose.
// ---------------------------------------------------------------------------
__global__ __launch_bounds__(256)
void k_transpose_v(const __bf16* __restrict__ v_ws, __bf16* __restrict__ vt_ws)
{
  __shared__ __bf16 tile[64][72];
  const int bh = blockIdx.x >> 5;
  const int tt = blockIdx.x & 31;
  const int tid = threadIdx.x;
  const __bf16* src = v_ws + ((size_t)bh * Tn + tt * 64) * Dn;
  #pragma unroll
  for (int it = 0; it < 2; ++it) {
    int gi = tid + it * 256;
    int row = gi >> 3, gg = gi & 7;
    *reinterpret_cast<bf16x8*>(&tile[row][gg * 8]) =
        *reinterpret_cast<const bf16x8*>(src + row * Dn + gg * 8);
  }
  __syncthreads();
  __bf16* dst = vt_ws + (size_t)bh * Dn * Tn + tt * 64;
  #pragma unroll
  for (int it = 0; it < 2; ++it) {
    int gi = tid + it * 256;
    int drow = gi >> 3, tg = gi & 7;
    bf16x8 vv;
    #pragma unroll
    for (int e = 0; e < 8; ++e) vv[e] = tile[tg * 8 + e][drow];
    *reinterpret_cast<bf16x8*>(dst + (size_t)drow * Tn + tg * 8) = vv;
  }
}

// ---------------------------------------------------------------------------
// Kernel 2: flash attention, swapped-operand 32x32 MFMA structure (log2 dom.)
// ---------------------------------------------------------------------------
__global__ __launch_bounds__(256, 2)
void k_flash(const __bf16* __restrict__ q_ws, const __bf16* __restrict__ k_ws,
             const __bf16* __restrict__ vt_ws, __bf16* __restrict__ ctx,
             float* __restrict__ stats)
{
  __shared__ __align__(16) char k_sm[8192];   // [64 s][64 d], 128B rows, swizzled
  __shared__ __align__(16) char v_sm[8192];   // [64 d][64 s], 128B rows, swizzled
  __shared__ __align__(16) float es_sm[4][32];

  const int tid = threadIdx.x;
  const int lane = tid & 63, w = tid >> 6;
  const int tl = lane & 31, hi = lane >> 5;
  const int bh = blockIdx.x >> 4;
  const int qt = blockIdx.x & 15;
  const int t0w = qt * 128 + w * 32;

  const __bf16* kbase  = k_ws + (size_t)bh * Tn * Dn;
  const __bf16* vtbase = vt_ws + (size_t)bh * Dn * Tn;

  bf16x8 qf[4];
  {
    const __bf16* qrow = q_ws + ((size_t)bh * Tn + t0w + tl) * Dn + hi * 8;
    #pragma unroll
    for (int c = 0; c < 4; ++c)
      qf[c] = *reinterpret_cast<const bf16x8*>(qrow + c * 16);
  }

  f32x16 accO0, accO1;
  #pragma unroll
  for (int i = 0; i < 16; ++i) { accO0[i] = 0.f; accO1[i] = 0.f; }
  float m_run = -INFINITY, l_run = 0.f;

  const int r0 = tid >> 3, s0 = tid & 7;
  const int ldso = ((s0 ^ (r0 & 7)) << 4);
  const int ko0 = r0 * 128 + ldso, ko1 = ko0 + 32 * 128;

  bf16x8 rk0 = *(const bf16x8*)(kbase + r0 * 64 + s0 * 8);
  bf16x8 rk1 = *(const bf16x8*)(kbase + (r0 + 32) * 64 + s0 * 8);
  bf16x8 rv0 = *(const bf16x8*)(vtbase + (size_t)r0 * Tn + s0 * 8);
  bf16x8 rv1 = *(const bf16x8*)(vtbase + (size_t)(r0 + 32) * Tn + s0 * 8);

  for (int st = 0; st < 32; ++st) {
    __syncthreads();
    *(bf16x8*)(k_sm + ko0) = rk0;
    *(bf16x8*)(k_sm + ko1) = rk1;
    *(bf16x8*)(v_sm + ko0) = rv0;
    *(bf16x8*)(v_sm + ko1) = rv1;
    __syncthreads();
    if (st + 1 < 32) {
      const __bf16* kn = kbase + (size_t)(st + 1) * 64 * Dn;
      const __bf16* vn = vtbase + (st + 1) * 64;
      rk0 = *(const bf16x8*)(kn + r0 * 64 + s0 * 8);
      rk1 = *(const bf16x8*)(kn + (r0 + 32) * 64 + s0 * 8);
      rv0 = *(const bf16x8*)(vn + (size_t)r0 * Tn + s0 * 8);
      rv1 = *(const bf16x8*)(vn + (size_t)(r0 + 32) * Tn + s0 * 8);
    }

    f32x16 sc0, sc1;
    #pragma unroll
    for (int i = 0; i < 16; ++i) { sc0[i] = 0.f; sc1[i] = 0.f; }
    const char* kr0 = k_sm + tl * 128;
    const char* kr1 = k_sm + (32 + tl) * 128;
    #pragma unroll
    for (int c = 0; c < 4; ++c) {
      const int off = (((2 * c + hi) ^ (tl & 7)) << 4);
      sc0 = MFMA32(*(const bf16x8*)(kr0 + off), qf[c], sc0);
      sc1 = MFMA32(*(const bf16x8*)(kr1 + off), qf[c], sc1);
    }

    float mx[8];
    #pragma unroll
    for (int i = 0; i < 8; ++i)
      mx[i] = fmaxf(fmaxf(sc0[i], sc0[i + 8]), fmaxf(sc1[i], sc1[i + 8]));
    float tm = fmaxf(fmaxf(fmaxf(mx[0], mx[1]), fmaxf(mx[2], mx[3])),
                     fmaxf(fmaxf(mx[4], mx[5]), fmaxf(mx[6], mx[7])));
    tm = fmaxf(tm, __shfl_xor(tm, 32, 64));
    const float mn = fmaxf(m_run, tm);
    const float es = EXP2(m_run - mn);
    m_run = mn;
    #pragma unroll
    for (int i = 0; i < 16; ++i) {
      sc0[i] = EXP2(sc0[i] - mn);
      sc1[i] = EXP2(sc1[i] - mn);
    }
    float p0s = 0.f, p1s = 0.f, p2s = 0.f, p3s = 0.f;
    #pragma unroll
    for (int i = 0; i < 16; i += 4) {
      p0s += sc0[i]     + sc1[i];
      p1s += sc0[i + 1] + sc1[i + 1];
      p2s += sc0[i + 2] + sc1[i + 2];
      p3s += sc0[i + 3] + sc1[i + 3];
    }
    float rs = (p0s + p1s) + (p2s + p3s);
    rs += __shfl_xor(rs, 32, 64);
    l_run = l_run * es + rs;

    es_sm[w][tl] = es;
    f32x4 esr[4];
    #pragma unroll
    for (int q = 0; q < 4; ++q)
      esr[q] = *(const f32x4*)&es_sm[w][8 * q + 4 * hi];
    #pragma unroll
    for (int q = 0; q < 4; ++q)
      #pragma unroll
      for (int rr = 0; rr < 4; ++rr) {
        accO0[q * 4 + rr] *= esr[q][rr];
        accO1[q * 4 + rr] *= esr[q][rr];
      }

    unsigned wA0[4], wB0[4], wA1[4], wB1[4];
    #pragma unroll
    for (int g = 0; g < 4; ++g) {
      wA0[g] = pack2(sc0[4 * g],     sc0[4 * g + 1]);
      wB0[g] = pack2(sc0[4 * g + 2], sc0[4 * g + 3]);
      wA1[g] = pack2(sc1[4 * g],     sc1[4 * g + 1]);
      wB1[g] = pack2(sc1[4 * g + 2], sc1[4 * g + 3]);
    }
    bf16x8 pa[2][2];
    #pragma unroll
    for (int sb = 0; sb < 2; ++sb) {
      const unsigned* WA = sb ? wA1 : wA0;
      const unsigned* WB = sb ? wB1 : wB0;
      #pragma unroll
      for (int c = 0; c < 2; ++c) {
        unsigned a0 = WA[2 * c], a1 = WA[2 * c + 1];
        unsigned b0 = WB[2 * c], b1 = WB[2 * c + 1];
        unsigned xa0 = __shfl_xor(a0, 32, 64);
        unsigned xa1 = __shfl_xor(a1, 32, 64);
        unsigned xb0 = __shfl_xor(b0, 32, 64);
        unsigned xb1 = __shfl_xor(b1, 32, 64);
        union { unsigned u[4]; bf16x8 v; } uu;
        uu.u[0] = hi ? xa1 : a0;
        uu.u[1] = hi ? xb1 : b0;
        uu.u[2] = hi ? a1 : xa0;
        uu.u[3] = hi ? b1 : xb0;
        pa[sb][c] = uu.v;
      }
    }

    const char* vr0 = v_sm + tl * 128;
    const char* vr1 = v_sm + (32 + tl) * 128;
    #pragma unroll
    for (int sb = 0; sb < 2; ++sb)
      #pragma unroll
      for (int c = 0; c < 2; ++c) {
        const int off = (((sb * 4 + c * 2 + hi) ^ (tl & 7)) << 4);
        accO0 = MFMA32(pa[sb][c], *(const bf16x8*)(vr0 + off), accO0);
        accO1 = MFMA32(pa[sb][c], *(const bf16x8*)(vr1 + off), accO1);
      }
  }

  const float linv = 1.0f / l_run;
  es_sm[w][tl] = linv;
  f32x4 lr[4];
  #pragma unroll
  for (int q = 0; q < 4; ++q)
    lr[q] = *(const f32x4*)&es_sm[w][8 * q + 4 * hi];
  const int b2 = bh >> 4, h = bh & 15;
  #pragma unroll
  for (int q = 0; q < 4; ++q)
    #pragma unroll
    for (int rr = 0; rr < 4; ++rr) {
      const int t = t0w + 8 * q + 4 * hi + rr;
      __bf16* cp = ctx + ((size_t)t * Bn + b2) * En + h * 64 + tl;
      cp[0]  = (__bf16)(accO0[q * 4 + rr] * lr[q][rr]);
      cp[32] = (__bf16)(accO1[q * 4 + rr] * lr[q][rr]);
    }
  if (hi == 0) {
    const int t = t0w + tl;
    f32x2 stv; stv[0] = m_run; stv[1] = l_run;
    *reinterpret_cast<f32x2*>(&stats[((size_t)bh * Tn + t) * 2]) = stv;
  }
}

// ---------------------------------------------------------------------------
// Kernel 3: avg attention weights (recompute QK^T; log2-domain stats).
// Block = 64x64 out tile; grid = 2 x 32 x 32 = 2048; 16 h-iters, 2 barriers ea.
// avg[t][s] = sum_h exp2(S_h[t][s] - adj_h[t]),  adj = m + log2(16*l).
// ---------------------------------------------------------------------------
__global__ __launch_bounds__(256)
void k_avgw(const __bf16* __restrict__ q_ws, const __bf16* __restrict__ k_ws,
            const float* __restrict__ stats, float* __restrict__ avg_out)
{
  __shared__ __align__(16) char q_sm[8192];   // [64 t][64 d], swizzled 128B rows
  __shared__ __align__(16) char k_sm[8192];   // [64 s][64 d], swizzled
  __shared__ __align__(16) float adj_sm[16][64];

  const int tid = threadIdx.x;
  const int lane = tid & 63, w = tid >> 6;
  const int tl = lane & 31, hi = lane >> 5;
  const int b2 = blockIdx.x >> 10;
  const int tt = (blockIdx.x >> 5) & 31;
  const int ss = blockIdx.x & 31;
  const int thalf = (w >> 1) * 32, shalf = (w & 1) * 32;

  // stage stats -> adj (once)
  #pragma unroll
  for (int it = 0; it < 4; ++it) {
    int idx = tid + it * 256;                     // h*64 + trow
    int h = idx >> 6, trow = idx & 63;
    f32x2 sv = *(const f32x2*)&stats[(((size_t)(b2 * Hn + h)) * Tn + tt * 64 + trow) * 2];
    adj_sm[h][trow] = sv[0] + LOG2(16.0f * sv[1]);
  }

  const size_t hstride = (size_t)Tn * Dn;
  const __bf16* qb = q_ws + ((size_t)(b2 * Hn) * Tn + tt * 64) * Dn;
  const __bf16* kb = k_ws + ((size_t)(b2 * Hn) * Tn + ss * 64) * Dn;

  const int r0 = tid >> 3, s0 = tid & 7;
  const int ldso = ((s0 ^ (r0 & 7)) << 4);
  const int ko0 = r0 * 128 + ldso, ko1 = ko0 + 32 * 128;

  bf16x8 rq0 = *(const bf16x8*)(qb + r0 * 64 + s0 * 8);
  bf16x8 rq1 = *(const bf16x8*)(qb + (r0 + 32) * 64 + s0 * 8);
  bf16x8 rk0 = *(const bf16x8*)(kb + r0 * 64 + s0 * 8);
  bf16x8 rk1 = *(const bf16x8*)(kb + (r0 + 32) * 64 + s0 * 8);

  f32x16 avg;
  #pragma unroll
  for (int i = 0; i < 16; ++i) avg[i] = 0.f;

  const char* qr = q_sm + (thalf + tl) * 128;
  const char* kr = k_sm + (shalf + tl) * 128;

  for (int h = 0; h < Hn; ++h) {
    __syncthreads();
    *(bf16x8*)(q_sm + ko0) = rq0;
    *(bf16x8*)(q_sm + ko1) = rq1;
    *(bf16x8*)(k_sm + ko0) = rk0;
    *(bf16x8*)(k_sm + ko1) = rk1;
    __syncthreads();
    if (h + 1 < Hn) {
      const __bf16* qn = qb + (size_t)(h + 1) * hstride;
      const __bf16* kn = kb + (size_t)(h + 1) * hstride;
      rq0 = *(const bf16x8*)(qn + r0 * 64 + s0 * 8);
      rq1 = *(const bf16x8*)(qn + (r0 + 32) * 64 + s0 * 8);
      rk0 = *(const bf16x8*)(kn + r0 * 64 + s0 * 8);
      rk1 = *(const bf16x8*)(kn + (r0 + 32) * 64 + s0 * 8);
    }

    f32x16 sc;
    #pragma unroll
    for (int i = 0; i < 16; ++i) sc[i] = 0.f;
    #pragma unroll
    for (int c = 0; c < 4; ++c) {
      const int off = (((2 * c + hi) ^ (tl & 7)) << 4);
      sc = MFMA32(*(const bf16x8*)(qr + off), *(const bf16x8*)(kr + off), sc);
    }

    #pragma unroll
    for (int q = 0; q < 4; ++q) {
      f32x4 ad = *(const f32x4*)&adj_sm[h][thalf + 8 * q + 4 * hi];
      #pragma unroll
      for (int r = 0; r < 4; ++r)
        avg[q * 4 + r] += EXP2(sc[q * 4 + r] - ad[r]);
    }
  }

  #pragma unroll
  for (int q = 0; q < 4; ++q)
    #pragma unroll
    for (int r = 0; r < 4; ++r) {
      int t = tt * 64 + thalf + 8 * q + 4 * hi + r;
      int s = ss * 64 + shalf + tl;
      avg_out[((size_t)(b2 * Tn + t)) * Tn + s] = avg[q * 4 + r];
    }
}

// ---------------------------------------------------------------------------
// Kernel 4: out projection. out[i,o] = ctx[i,:] . W[o,:] + bias[o], fp32 out.
// ---------------------------------------------------------------------------
__global__ __launch_bounds__(256)
void k_outproj(const __bf16* __restrict__ ctx, const float* __restrict__ W,
               const float* __restrict__ bias, float* __restrict__ out)
{
  __shared__ bf16x8 Asm[128 * 4];
  __shared__ bf16x8 Bsm[128 * 4];
  const int tid = threadIdx.x;
  const int lane = tid & 63, w = tid >> 6;
  const int wr = w >> 1, wc = w & 1;
  const int ag = lane >> 4, lr = lane & 15;
  const int mBase = blockIdx.x * 128;
  const int oBase = blockIdx.y * 128;

  f32x4 acc[4][4];
  #pragma unroll
  for (int i = 0; i < 4; ++i)
    #pragma unroll
    for (int j = 0; j < 4; ++j) { f32x4 z = {0.f,0.f,0.f,0.f}; acc[i][j] = z; }

  for (int kk = 0; kk < En; kk += 32) {
    __syncthreads();
    #pragma unroll
    for (int it = 0; it < 2; ++it) {
      int gi = tid + it * 256;
      int row = gi >> 2, gg = gi & 3;
      bf16x8 av = *reinterpret_cast<const bf16x8*>(
          ctx + (size_t)(mBase + row) * En + kk + gg * 8);
      const float* pb = W + (size_t)(oBase + row) * En + kk + gg * 8;
      f32x4 b0 = *reinterpret_cast<const f32x4*>(pb);
      f32x4 b1 = *reinterpret_cast<const f32x4*>(pb + 4);
      bf16x8 bv;
      #pragma unroll
      for (int e = 0; e < 4; ++e) { bv[e] = (__bf16)b0[e]; bv[e + 4] = (__bf16)b1[e]; }
      int sg = gg ^ ((row >> 1) & 3);
      Asm[row * 4 + sg] = av;
      Bsm[row * 4 + sg] = bv;
    }
    __syncthreads();
    bf16x8 af[4], bfr[4];
    #pragma unroll
    for (int mb = 0; mb < 4; ++mb) {
      int row = wr * 64 + mb * 16 + lr;
      af[mb] = Asm[row * 4 + (ag ^ ((row >> 1) & 3))];
    }
    #pragma unroll
    for (int nb = 0; nb < 4; ++nb) {
      int row = wc * 64 + nb * 16 + lr;
      bfr[nb] = Bsm[row * 4 + (ag ^ ((row >> 1) & 3))];
    }
    #pragma unroll
    for (int mb = 0; mb < 4; ++mb)
      #pragma unroll
      for (int nb = 0; nb < 4; ++nb)
        acc[mb][nb] = MFMA16(af[mb], bfr[nb], acc[mb][nb]);
  }

  #pragma unroll
  for (int nb = 0; nb < 4; ++nb) {
    int o = oBase + wc * 64 + nb * 16 + lr;
    float bv = bias[o];
    #pragma unroll
    for (int mb = 0; mb < 4; ++mb)
      #pragma unroll
      for (int r = 0; r < 4; ++r) {
        int i = mBase + wr * 64 + mb * 16 + ag * 4 + r;
        out[(size_t)i * En + o] = acc[mb][nb][r] + bv;
      }
  }
}

// ---------------------------------------------------------------------------
extern "C" void kernel_launch(void* const* d_in, const int* in_sizes, int n_in,
                              void* d_out, int out_size, void* d_ws, size_t ws_size,
                              hipStream_t stream)
{
  (void)in_sizes; (void)n_in; (void)out_size; (void)ws_size;
  const float* query = (const float*)d_in[0];
  const float* key   = (const float*)d_in[1];
  const float* value = (const float*)d_in[2];
  const float* in_w  = (const float*)d_in[3];
  const float* in_b  = (const float*)d_in[4];
  const float* out_w = (const float*)d_in[5];
  const float* out_b = (const float*)d_in[6];

  float* attn_out = (float*)d_out;                                 // [T,B,E]
  float* avg_out  = (float*)d_out + (size_t)Tn * Bn * En;          // [B,T,S]

  char* ws = (char*)d_ws;
  __bf16* q_ws  = (__bf16*)(ws);                    // [B,H,T,D] bf16, 8 MB
  __bf16* k_ws  = (__bf16*)(ws + (8u  << 20));      // 8 MB
  __bf16* v_ws  = (__bf16*)(ws + (16u << 20));      // 8 MB
  __bf16* vt_ws = (__bf16*)(ws + (24u << 20));      // [B,H,D,T] 8 MB
  __bf16* ctx   = (__bf16*)(ws + (32u << 20));      // [T,B,E] 8 MB
  float*  stats = (float*)(ws + (40u << 20));       // [B,H,T,2] 512 KB

  k_qkv<<<dim3(32, 24), 256, 0, stream>>>(query, key, value, in_w, in_b,
                                          q_ws, k_ws, v_ws);
  k_transpose_v<<<1024, 256, 0, stream>>>(v_ws, vt_ws);
  k_flash<<<512, 256, 0, stream>>>(q_ws, k_ws, vt_ws, ctx, stats);
  k_avgw<<<2048, 256, 0, stream>>>(q_ws, k_ws, stats, avg_out);
  k_outproj<<<dim3(32, 8), 256, 0, stream>>>(ctx, out_w, out_b, attn_out);
}